// Round 1
// baseline (1153.585 us; speedup 1.0000x reference)
//
#include <hip/hip_runtime.h>
#include <hip/hip_bf16.h>

typedef float f32x4 __attribute__((ext_vector_type(4)));
typedef short s16x8 __attribute__((ext_vector_type(8)));
typedef unsigned short u16;

#define N_TOK 4096
#define DIM 1024
#define HID 4096
#define NE 8

__device__ __forceinline__ u16 f2bf(float f) {
  unsigned u = __float_as_uint(f);
  u += 0x7fffu + ((u >> 16) & 1u);   // round-to-nearest-even
  return (u16)(u >> 16);
}

__global__ void init_kernel(int* counts) {
  if (threadIdx.x < NE) counts[threadIdx.x] = 0;
}

__global__ __launch_bounds__(256) void gate_kernel(
    const float* __restrict__ x, const float* __restrict__ gw,
    const float* __restrict__ gb, int* __restrict__ counts,
    int* __restrict__ tlist, int* __restrict__ eid, int* __restrict__ pos,
    float* __restrict__ wgt) {
  int t = blockIdx.x * 4 + (threadIdx.x >> 6);
  int lane = threadIdx.x & 63;
  float acc[NE];
  #pragma unroll
  for (int e = 0; e < NE; ++e) acc[e] = 0.f;
  const float* xr = x + (size_t)t * DIM;
  for (int d = lane; d < DIM; d += 64) {
    float xv = xr[d];
    const float* g = gw + d * NE;
    #pragma unroll
    for (int e = 0; e < NE; ++e) acc[e] += xv * g[e];
  }
  #pragma unroll
  for (int off = 32; off > 0; off >>= 1) {
    #pragma unroll
    for (int e = 0; e < NE; ++e) acc[e] += __shfl_down(acc[e], off);
  }
  if (lane == 0) {
    #pragma unroll
    for (int e = 0; e < NE; ++e) acc[e] += gb[e];
    int i0 = 0; float v0 = acc[0];
    #pragma unroll
    for (int e = 1; e < NE; ++e) if (acc[e] > v0) { v0 = acc[e]; i0 = e; }
    int i1 = -1; float v1 = -1e30f;
    #pragma unroll
    for (int e = 0; e < NE; ++e) if (e != i0 && acc[e] > v1) { v1 = acc[e]; i1 = e; }
    float z = expf(v1 - v0);            // v0 >= v1
    float s0 = 1.f / (1.f + z);
    float s1 = z / (1.f + z);
    int p0 = atomicAdd(&counts[i0], 1);
    tlist[i0 * N_TOK + p0] = t * 2 + 0;
    eid[2 * t] = i0; pos[2 * t] = p0; wgt[2 * t] = s0;
    int p1 = atomicAdd(&counts[i1], 1);
    tlist[i1 * N_TOK + p1] = t * 2 + 1;
    eid[2 * t + 1] = i1; pos[2 * t + 1] = p1; wgt[2 * t + 1] = s1;
  }
}

__global__ void scan_kernel(const int* __restrict__ counts, int* __restrict__ offs) {
  if (threadIdx.x == 0) {
    int s = 0;
    for (int e = 0; e < NE; ++e) { offs[e] = s; s += counts[e]; }
    offs[NE] = s;
  }
}

// GEMM1: h[slot, H] = relu(x[token, D] * w1[e, D, H] + b1[e, H]) -> bf16
__global__ __launch_bounds__(256) void gemm1_kernel(
    const float* __restrict__ x, const float* __restrict__ w1,
    const float* __restrict__ b1, const int* __restrict__ counts,
    const int* __restrict__ offs, const int* __restrict__ tlist,
    u16* __restrict__ hbuf) {
  int e = blockIdx.z;
  int ne = counts[e];
  int m0 = blockIdx.x * 128;
  if (m0 >= ne) return;
  int n0 = blockIdx.y * 128;
  int tid = threadIdx.x;

  __shared__ u16 Als[128 * 32];
  __shared__ u16 Bls[128 * 32];

  int ra = tid >> 1;
  int acb = (tid & 1) * 16;
  bool aok = (m0 + ra) < ne;
  size_t xbase = 0;
  if (aok) xbase = (size_t)(tlist[e * N_TOK + m0 + ra] >> 1) * DIM;

  int bc = tid & 127;
  int bkk = (tid >> 7) * 16;
  const float* bsrc = w1 + (size_t)e * (DIM * HID) + n0 + bc;

  int lane = tid & 63;
  int wv = tid >> 6;
  int wr = (wv >> 1) * 64, wc = (wv & 1) * 64;

  f32x4 acc[4][4];
  #pragma unroll
  for (int m = 0; m < 4; ++m)
    #pragma unroll
    for (int n = 0; n < 4; ++n) { f32x4 z = {0.f, 0.f, 0.f, 0.f}; acc[m][n] = z; }

  for (int k0 = 0; k0 < DIM; k0 += 32) {
    float aregs[16];
    if (aok) {
      const float4* ap = (const float4*)(x + xbase + k0 + acb);
      #pragma unroll
      for (int j = 0; j < 4; ++j) {
        float4 v = ap[j];
        aregs[4 * j + 0] = v.x; aregs[4 * j + 1] = v.y;
        aregs[4 * j + 2] = v.z; aregs[4 * j + 3] = v.w;
      }
    } else {
      #pragma unroll
      for (int j = 0; j < 16; ++j) aregs[j] = 0.f;
    }
    float bregs[16];
    #pragma unroll
    for (int j = 0; j < 16; ++j)
      bregs[j] = bsrc[(size_t)(k0 + bkk + j) * HID];

    __syncthreads();
    s16x8 av0, av1, bv0, bv1;
    #pragma unroll
    for (int j = 0; j < 8; ++j) {
      av0[j] = (short)f2bf(aregs[j]);     av1[j] = (short)f2bf(aregs[8 + j]);
      bv0[j] = (short)f2bf(bregs[j]);     bv1[j] = (short)f2bf(bregs[8 + j]);
    }
    int s0 = acb >> 3;
    *(s16x8*)&Als[ra * 32 + ((s0    ) ^ (ra & 3)) * 8] = av0;
    *(s16x8*)&Als[ra * 32 + ((s0 + 1) ^ (ra & 3)) * 8] = av1;
    int t0 = bkk >> 3;
    *(s16x8*)&Bls[bc * 32 + ((t0    ) ^ (bc & 3)) * 8] = bv0;
    *(s16x8*)&Bls[bc * 32 + ((t0 + 1) ^ (bc & 3)) * 8] = bv1;
    __syncthreads();

    s16x8 af[4], bfr[4];
    #pragma unroll
    for (int m = 0; m < 4; ++m) {
      int row = wr + m * 16 + (lane & 15);
      int slot = (lane >> 4) ^ (row & 3);
      af[m] = *(const s16x8*)&Als[row * 32 + slot * 8];
    }
    #pragma unroll
    for (int n = 0; n < 4; ++n) {
      int col = wc + n * 16 + (lane & 15);
      int slot = (lane >> 4) ^ (col & 3);
      bfr[n] = *(const s16x8*)&Bls[col * 32 + slot * 8];
    }
    #pragma unroll
    for (int m = 0; m < 4; ++m)
      #pragma unroll
      for (int n = 0; n < 4; ++n)
        acc[m][n] = __builtin_amdgcn_mfma_f32_16x16x32_bf16(af[m], bfr[n], acc[m][n], 0, 0, 0);
  }

  int boff = offs[e];
  #pragma unroll
  for (int m = 0; m < 4; ++m) {
    #pragma unroll
    for (int j = 0; j < 4; ++j) {
      int row = wr + m * 16 + (lane >> 4) * 4 + j;
      if (m0 + row < ne) {
        size_t gr = (size_t)(boff + m0 + row) * HID + n0;
        #pragma unroll
        for (int n = 0; n < 4; ++n) {
          int col = wc + n * 16 + (lane & 15);
          float v = acc[m][n][j] + b1[e * HID + n0 + col];
          hbuf[gr + col] = f2bf(fmaxf(v, 0.f));
        }
      }
    }
  }
}

// GEMM2: y[slot, D] = h[slot, H] * w2[e, H, D] + b2[e, D] -> fp32
__global__ __launch_bounds__(256) void gemm2_kernel(
    const u16* __restrict__ hbuf, const float* __restrict__ w2,
    const float* __restrict__ b2, const int* __restrict__ counts,
    const int* __restrict__ offs, float* __restrict__ ybuf) {
  int e = blockIdx.z;
  int ne = counts[e];
  int m0 = blockIdx.x * 128;
  if (m0 >= ne) return;
  int n0 = blockIdx.y * 128;
  int tid = threadIdx.x;
  int boff = offs[e];

  __shared__ u16 Als[128 * 32];
  __shared__ u16 Bls[128 * 32];

  int ra = tid >> 1;
  int acb = (tid & 1) * 16;
  const u16* asrc = hbuf + (size_t)(boff + m0 + ra) * HID + acb;

  int bc = tid & 127;
  int bkk = (tid >> 7) * 16;
  const float* bsrc = w2 + (size_t)e * (HID * DIM) + n0 + bc;

  int lane = tid & 63;
  int wv = tid >> 6;
  int wr = (wv >> 1) * 64, wc = (wv & 1) * 64;

  f32x4 acc[4][4];
  #pragma unroll
  for (int m = 0; m < 4; ++m)
    #pragma unroll
    for (int n = 0; n < 4; ++n) { f32x4 z = {0.f, 0.f, 0.f, 0.f}; acc[m][n] = z; }

  for (int k0 = 0; k0 < HID; k0 += 32) {
    s16x8 av0 = *(const s16x8*)(asrc + k0);
    s16x8 av1 = *(const s16x8*)(asrc + k0 + 8);
    float bregs[16];
    #pragma unroll
    for (int j = 0; j < 16; ++j)
      bregs[j] = bsrc[(size_t)(k0 + bkk + j) * DIM];

    __syncthreads();
    s16x8 bv0, bv1;
    #pragma unroll
    for (int j = 0; j < 8; ++j) {
      bv0[j] = (short)f2bf(bregs[j]); bv1[j] = (short)f2bf(bregs[8 + j]);
    }
    int s0 = acb >> 3;
    *(s16x8*)&Als[ra * 32 + ((s0    ) ^ (ra & 3)) * 8] = av0;
    *(s16x8*)&Als[ra * 32 + ((s0 + 1) ^ (ra & 3)) * 8] = av1;
    int t0 = bkk >> 3;
    *(s16x8*)&Bls[bc * 32 + ((t0    ) ^ (bc & 3)) * 8] = bv0;
    *(s16x8*)&Bls[bc * 32 + ((t0 + 1) ^ (bc & 3)) * 8] = bv1;
    __syncthreads();

    s16x8 af[4], bfr[4];
    #pragma unroll
    for (int m = 0; m < 4; ++m) {
      int row = wr + m * 16 + (lane & 15);
      int slot = (lane >> 4) ^ (row & 3);
      af[m] = *(const s16x8*)&Als[row * 32 + slot * 8];
    }
    #pragma unroll
    for (int n = 0; n < 4; ++n) {
      int col = wc + n * 16 + (lane & 15);
      int slot = (lane >> 4) ^ (col & 3);
      bfr[n] = *(const s16x8*)&Bls[col * 32 + slot * 8];
    }
    #pragma unroll
    for (int m = 0; m < 4; ++m)
      #pragma unroll
      for (int n = 0; n < 4; ++n)
        acc[m][n] = __builtin_amdgcn_mfma_f32_16x16x32_bf16(af[m], bfr[n], acc[m][n], 0, 0, 0);
  }

  #pragma unroll
  for (int m = 0; m < 4; ++m) {
    #pragma unroll
    for (int j = 0; j < 4; ++j) {
      int row = wr + m * 16 + (lane >> 4) * 4 + j;
      if (m0 + row < ne) {
        size_t gr = (size_t)(boff + m0 + row) * DIM + n0;
        #pragma unroll
        for (int n = 0; n < 4; ++n) {
          int col = wc + n * 16 + (lane & 15);
          ybuf[gr + col] = acc[m][n][j] + b2[e * DIM + n0 + col];
        }
      }
    }
  }
}

__global__ __launch_bounds__(256) void combine_kernel(
    const int* __restrict__ eid, const int* __restrict__ pos,
    const float* __restrict__ wgt, const int* __restrict__ offs,
    const float* __restrict__ ybuf, float* __restrict__ out) {
  int t = blockIdx.x;
  int e0 = eid[2 * t], e1 = eid[2 * t + 1];
  float w0 = wgt[2 * t], w1v = wgt[2 * t + 1];
  size_t g0 = (size_t)(offs[e0] + pos[2 * t]) * DIM;
  size_t g1 = (size_t)(offs[e1] + pos[2 * t + 1]) * DIM;
  int d = threadIdx.x * 4;
  float4 y0 = *(const float4*)&ybuf[g0 + d];
  float4 y1 = *(const float4*)&ybuf[g1 + d];
  float4 o;
  o.x = w0 * y0.x + w1v * y1.x;
  o.y = w0 * y0.y + w1v * y1.y;
  o.z = w0 * y0.z + w1v * y1.z;
  o.w = w0 * y0.w + w1v * y1.w;
  *(float4*)&out[(size_t)t * DIM + d] = o;
}

extern "C" void kernel_launch(void* const* d_in, const int* in_sizes, int n_in,
                              void* d_out, int out_size, void* d_ws, size_t ws_size,
                              hipStream_t stream) {
  const float* x  = (const float*)d_in[0];
  const float* gw = (const float*)d_in[1];
  const float* gb = (const float*)d_in[2];
  const float* w1 = (const float*)d_in[3];
  const float* b1 = (const float*)d_in[4];
  const float* w2 = (const float*)d_in[5];
  const float* b2 = (const float*)d_in[6];
  float* out = (float*)d_out;

  char* ws = (char*)d_ws;
  // layout: hbuf 64MB | ybuf 32MB | eid/pos/wgt 96KB | counts | offs | tlist 128KB
  u16*   hbuf   = (u16*)(ws);
  float* ybuf   = (float*)(ws + 67108864);
  int*   eid    = (int*)(ws + 100663296);
  int*   pos    = (int*)(ws + 100696064);
  float* wgt    = (float*)(ws + 100728832);
  int*   counts = (int*)(ws + 100761600);
  int*   offs   = (int*)(ws + 100761664);
  int*   tlist  = (int*)(ws + 100761728);

  init_kernel<<<1, 64, 0, stream>>>(counts);
  gate_kernel<<<N_TOK / 4, 256, 0, stream>>>(x, gw, gb, counts, tlist, eid, pos, wgt);
  scan_kernel<<<1, 64, 0, stream>>>(counts, offs);
  gemm1_kernel<<<dim3(32, 32, NE), 256, 0, stream>>>(x, w1, b1, counts, offs, tlist, hbuf);
  gemm2_kernel<<<dim3(32, 8, NE), 256, 0, stream>>>(hbuf, w2, b2, counts, offs, ybuf);
  combine_kernel<<<N_TOK, 256, 0, stream>>>(eid, pos, wgt, offs, ybuf, out);
}

// Round 2
// 832.331 us; speedup vs baseline: 1.3860x; 1.3860x over previous
//
#include <hip/hip_runtime.h>
#include <hip/hip_bf16.h>

typedef float f32x4 __attribute__((ext_vector_type(4)));
typedef short s16x8 __attribute__((ext_vector_type(8)));
typedef unsigned short u16;
typedef unsigned short u16x4 __attribute__((ext_vector_type(4)));

#define N_TOK 4096
#define DIM 1024
#define HID 4096
#define NE 8

__device__ __forceinline__ u16 f2bf(float f) {
  unsigned u = __float_as_uint(f);
  u += 0x7fffu + ((u >> 16) & 1u);   // round-to-nearest-even
  return (u16)(u >> 16);
}

__device__ __forceinline__ void gload16(const u16* g, u16* l) {
  __builtin_amdgcn_global_load_lds(
      (const __attribute__((address_space(1))) unsigned int*)g,
      (__attribute__((address_space(3))) unsigned int*)l, 16, 0, 0);
}

__global__ void init_kernel(int* counts) {
  if (threadIdx.x < NE) counts[threadIdx.x] = 0;
}

__global__ __launch_bounds__(256) void gate_kernel(
    const float* __restrict__ x, const float* __restrict__ gw,
    const float* __restrict__ gb, int* __restrict__ counts,
    int* __restrict__ tlist, int* __restrict__ eid, int* __restrict__ pos,
    float* __restrict__ wgt) {
  int t = blockIdx.x * 4 + (threadIdx.x >> 6);
  int lane = threadIdx.x & 63;
  float acc[NE];
  #pragma unroll
  for (int e = 0; e < NE; ++e) acc[e] = 0.f;
  const float* xr = x + (size_t)t * DIM;
  for (int d = lane; d < DIM; d += 64) {
    float xv = xr[d];
    const float* g = gw + d * NE;
    #pragma unroll
    for (int e = 0; e < NE; ++e) acc[e] += xv * g[e];
  }
  #pragma unroll
  for (int off = 32; off > 0; off >>= 1) {
    #pragma unroll
    for (int e = 0; e < NE; ++e) acc[e] += __shfl_down(acc[e], off);
  }
  if (lane == 0) {
    #pragma unroll
    for (int e = 0; e < NE; ++e) acc[e] += gb[e];
    int i0 = 0; float v0 = acc[0];
    #pragma unroll
    for (int e = 1; e < NE; ++e) if (acc[e] > v0) { v0 = acc[e]; i0 = e; }
    int i1 = -1; float v1 = -1e30f;
    #pragma unroll
    for (int e = 0; e < NE; ++e) if (e != i0 && acc[e] > v1) { v1 = acc[e]; i1 = e; }
    float z = expf(v1 - v0);            // v0 >= v1
    float s0 = 1.f / (1.f + z);
    float s1 = z / (1.f + z);
    int p0 = atomicAdd(&counts[i0], 1);
    tlist[i0 * N_TOK + p0] = t * 2 + 0;
    eid[2 * t] = i0; pos[2 * t] = p0; wgt[2 * t] = s0;
    int p1 = atomicAdd(&counts[i1], 1);
    tlist[i1 * N_TOK + p1] = t * 2 + 1;
    eid[2 * t + 1] = i1; pos[2 * t + 1] = p1; wgt[2 * t + 1] = s1;
  }
}

__global__ void scan_kernel(const int* __restrict__ counts, int* __restrict__ offs) {
  if (threadIdx.x == 0) {
    int s = 0;
    for (int e = 0; e < NE; ++e) { offs[e] = s; s += counts[e]; }
    offs[NE] = s;
  }
}

// x (fp32) -> xb (bf16), elementwise
__global__ __launch_bounds__(256) void x2bf_kernel(const float* __restrict__ x,
                                                   u16* __restrict__ xb) {
  int i = (blockIdx.x * 256 + threadIdx.x) * 4;
  float4 v = *(const float4*)&x[i];
  u16x4 o = {f2bf(v.x), f2bf(v.y), f2bf(v.z), f2bf(v.w)};
  *(u16x4*)&xb[i] = o;
}

// in[e][R][C] fp32 -> out[e][C][R] bf16 (64x64 LDS tile transpose)
__global__ __launch_bounds__(256) void transpose_bf16_kernel(
    const float* __restrict__ in, u16* __restrict__ out, int R, int C) {
  __shared__ u16 tile[64][65];
  int e = blockIdx.z;
  int c0 = blockIdx.x * 64, r0 = blockIdx.y * 64;
  int tid = threadIdx.x;
  int rr = tid >> 4;          // 0..15
  int cc = (tid & 15) * 4;    // 0..60
  const float* src = in + (size_t)e * R * C + (size_t)r0 * C + c0;
  #pragma unroll
  for (int rd = 0; rd < 4; ++rd) {
    int r = rd * 16 + rr;
    float4 v = *(const float4*)&src[(size_t)r * C + cc];
    tile[r][cc + 0] = f2bf(v.x);
    tile[r][cc + 1] = f2bf(v.y);
    tile[r][cc + 2] = f2bf(v.z);
    tile[r][cc + 3] = f2bf(v.w);
  }
  __syncthreads();
  u16* dst = out + (size_t)e * R * C + (size_t)c0 * R + r0;
  #pragma unroll
  for (int rd = 0; rd < 4; ++rd) {
    int oc = rd * 16 + rr;    // output row (= input col)
    u16x4 o;
    o[0] = tile[cc + 0][oc];
    o[1] = tile[cc + 1][oc];
    o[2] = tile[cc + 2][oc];
    o[3] = tile[cc + 3][oc];
    *(u16x4*)&dst[(size_t)oc * R + cc] = o;
  }
}

// GEMM1: h[slot, H] = relu(x[token, D] * w1t[e]^T + b1[e]) -> bf16
// A: xb gathered rows [128][32] bf16, B: w1t[e][H][D] rows [128][32] bf16
__global__ __launch_bounds__(256) void gemm1_kernel(
    const u16* __restrict__ xb, const u16* __restrict__ w1t,
    const float* __restrict__ b1, const int* __restrict__ counts,
    const int* __restrict__ offs, const int* __restrict__ tlist,
    u16* __restrict__ hbuf) {
  int e = blockIdx.z;
  int ne = counts[e];
  int m0 = blockIdx.x * 128;
  if (m0 >= ne) return;
  int n0 = blockIdx.y * 128;
  int tid = threadIdx.x;

  __shared__ u16 Als[128 * 32];
  __shared__ u16 Bls[128 * 32];

  int sr = tid >> 2;          // 0..63 : row within 64-row half
  int sc = (tid & 3) * 8;     // k element offset for 16B chunk
  const u16* aAdr[2];
  const u16* bAdr[2];
  u16* aLds[2];
  u16* bLds[2];
  #pragma unroll
  for (int r = 0; r < 2; ++r) {
    int tr = m0 + r * 64 + sr;
    int idx = tr < ne ? tr : ne - 1;
    int token = tlist[e * N_TOK + idx] >> 1;
    aAdr[r] = xb + (size_t)token * DIM + sc;
    int nr = n0 + r * 64 + sr;
    bAdr[r] = w1t + ((size_t)e * HID + nr) * DIM + sc;
    aLds[r] = &Als[r * 2048 + tid * 8];
    bLds[r] = &Bls[r * 2048 + tid * 8];
  }

  int lane = tid & 63;
  int wv = tid >> 6;
  int wr = (wv >> 1) * 64, wc = (wv & 1) * 64;
  int fr = lane & 15, fq = lane >> 4;

  f32x4 acc[4][4];
  #pragma unroll
  for (int m = 0; m < 4; ++m)
    #pragma unroll
    for (int n = 0; n < 4; ++n) { f32x4 z = {0.f, 0.f, 0.f, 0.f}; acc[m][n] = z; }

  for (int k0 = 0; k0 < DIM; k0 += 32) {
    __syncthreads();
    gload16(aAdr[0] + k0, aLds[0]);
    gload16(aAdr[1] + k0, aLds[1]);
    gload16(bAdr[0] + k0, bLds[0]);
    gload16(bAdr[1] + k0, bLds[1]);
    __syncthreads();
    s16x8 af[4], bfr[4];
    #pragma unroll
    for (int m = 0; m < 4; ++m)
      af[m] = *(const s16x8*)&Als[(wr + m * 16 + fr) * 32 + fq * 8];
    #pragma unroll
    for (int n = 0; n < 4; ++n)
      bfr[n] = *(const s16x8*)&Bls[(wc + n * 16 + fr) * 32 + fq * 8];
    #pragma unroll
    for (int m = 0; m < 4; ++m)
      #pragma unroll
      for (int n = 0; n < 4; ++n)
        acc[m][n] = __builtin_amdgcn_mfma_f32_16x16x32_bf16(af[m], bfr[n], acc[m][n], 0, 0, 0);
  }

  int boff = offs[e];
  float bias[4];
  #pragma unroll
  for (int n = 0; n < 4; ++n) bias[n] = b1[e * HID + n0 + wc + n * 16 + fr];
  #pragma unroll
  for (int m = 0; m < 4; ++m) {
    #pragma unroll
    for (int j = 0; j < 4; ++j) {
      int row = wr + m * 16 + fq * 4 + j;
      if (m0 + row < ne) {
        u16* hr = hbuf + (size_t)(boff + m0 + row) * HID + n0;
        #pragma unroll
        for (int n = 0; n < 4; ++n) {
          int col = wc + n * 16 + fr;
          float v = acc[m][n][j] + bias[n];
          hr[col] = f2bf(fmaxf(v, 0.f));
        }
      }
    }
  }
}

// GEMM2: y[slot, D] = h[slot, H] * w2t[e]^T + b2[e] -> fp32
__global__ __launch_bounds__(256) void gemm2_kernel(
    const u16* __restrict__ hbuf, const u16* __restrict__ w2t,
    const float* __restrict__ b2, const int* __restrict__ counts,
    const int* __restrict__ offs, float* __restrict__ ybuf) {
  int e = blockIdx.z;
  int ne = counts[e];
  int m0 = blockIdx.x * 128;
  if (m0 >= ne) return;
  int n0 = blockIdx.y * 128;
  int tid = threadIdx.x;
  int boff = offs[e];

  __shared__ u16 Als[128 * 32];
  __shared__ u16 Bls[128 * 32];

  int sr = tid >> 2;
  int sc = (tid & 3) * 8;
  const u16* aAdr[2];
  const u16* bAdr[2];
  u16* aLds[2];
  u16* bLds[2];
  #pragma unroll
  for (int r = 0; r < 2; ++r) {
    int ar = m0 + r * 64 + sr;
    int idx = ar < ne ? ar : ne - 1;
    aAdr[r] = hbuf + (size_t)(boff + idx) * HID + sc;
    int nr = n0 + r * 64 + sr;
    bAdr[r] = w2t + ((size_t)e * DIM + nr) * HID + sc;
    aLds[r] = &Als[r * 2048 + tid * 8];
    bLds[r] = &Bls[r * 2048 + tid * 8];
  }

  int lane = tid & 63;
  int wv = tid >> 6;
  int wr = (wv >> 1) * 64, wc = (wv & 1) * 64;
  int fr = lane & 15, fq = lane >> 4;

  f32x4 acc[4][4];
  #pragma unroll
  for (int m = 0; m < 4; ++m)
    #pragma unroll
    for (int n = 0; n < 4; ++n) { f32x4 z = {0.f, 0.f, 0.f, 0.f}; acc[m][n] = z; }

  for (int k0 = 0; k0 < HID; k0 += 32) {
    __syncthreads();
    gload16(aAdr[0] + k0, aLds[0]);
    gload16(aAdr[1] + k0, aLds[1]);
    gload16(bAdr[0] + k0, bLds[0]);
    gload16(bAdr[1] + k0, bLds[1]);
    __syncthreads();
    s16x8 af[4], bfr[4];
    #pragma unroll
    for (int m = 0; m < 4; ++m)
      af[m] = *(const s16x8*)&Als[(wr + m * 16 + fr) * 32 + fq * 8];
    #pragma unroll
    for (int n = 0; n < 4; ++n)
      bfr[n] = *(const s16x8*)&Bls[(wc + n * 16 + fr) * 32 + fq * 8];
    #pragma unroll
    for (int m = 0; m < 4; ++m)
      #pragma unroll
      for (int n = 0; n < 4; ++n)
        acc[m][n] = __builtin_amdgcn_mfma_f32_16x16x32_bf16(af[m], bfr[n], acc[m][n], 0, 0, 0);
  }

  float bias[4];
  #pragma unroll
  for (int n = 0; n < 4; ++n) bias[n] = b2[e * DIM + n0 + wc + n * 16 + fr];
  #pragma unroll
  for (int m = 0; m < 4; ++m) {
    #pragma unroll
    for (int j = 0; j < 4; ++j) {
      int row = wr + m * 16 + fq * 4 + j;
      if (m0 + row < ne) {
        float* yr = ybuf + (size_t)(boff + m0 + row) * DIM + n0;
        #pragma unroll
        for (int n = 0; n < 4; ++n) {
          int col = wc + n * 16 + fr;
          yr[col] = acc[m][n][j] + bias[n];
        }
      }
    }
  }
}

__global__ __launch_bounds__(256) void combine_kernel(
    const int* __restrict__ eid, const int* __restrict__ pos,
    const float* __restrict__ wgt, const int* __restrict__ offs,
    const float* __restrict__ ybuf, float* __restrict__ out) {
  int t = blockIdx.x;
  int e0 = eid[2 * t], e1 = eid[2 * t + 1];
  float w0 = wgt[2 * t], w1v = wgt[2 * t + 1];
  size_t g0 = (size_t)(offs[e0] + pos[2 * t]) * DIM;
  size_t g1 = (size_t)(offs[e1] + pos[2 * t + 1]) * DIM;
  int d = threadIdx.x * 4;
  float4 y0 = *(const float4*)&ybuf[g0 + d];
  float4 y1 = *(const float4*)&ybuf[g1 + d];
  float4 o;
  o.x = w0 * y0.x + w1v * y1.x;
  o.y = w0 * y0.y + w1v * y1.y;
  o.z = w0 * y0.z + w1v * y1.z;
  o.w = w0 * y0.w + w1v * y1.w;
  *(float4*)&out[(size_t)t * DIM + d] = o;
}

extern "C" void kernel_launch(void* const* d_in, const int* in_sizes, int n_in,
                              void* d_out, int out_size, void* d_ws, size_t ws_size,
                              hipStream_t stream) {
  const float* x  = (const float*)d_in[0];
  const float* gw = (const float*)d_in[1];
  const float* gb = (const float*)d_in[2];
  const float* w1 = (const float*)d_in[3];
  const float* b1 = (const float*)d_in[4];
  const float* w2 = (const float*)d_in[5];
  const float* b2 = (const float*)d_in[6];
  float* out = (float*)d_out;

  char* ws = (char*)d_ws;
  const size_t MB = 1ull << 20;
  // layout: w1t 64MB | w2t 64MB | xb 8MB | hbuf 64MB | ybuf 32MB | meta
  u16*   w1t    = (u16*)(ws);
  u16*   w2t    = (u16*)(ws + 64 * MB);
  u16*   xb     = (u16*)(ws + 128 * MB);
  u16*   hbuf   = (u16*)(ws + 136 * MB);
  float* ybuf   = (float*)(ws + 200 * MB);
  int*   eid    = (int*)(ws + 232 * MB);
  int*   pos    = (int*)(ws + 232 * MB + 32 * 1024);
  float* wgt    = (float*)(ws + 232 * MB + 64 * 1024);
  int*   counts = (int*)(ws + 232 * MB + 96 * 1024);
  int*   offs   = (int*)(ws + 232 * MB + 96 * 1024 + 256);
  int*   tlist  = (int*)(ws + 232 * MB + 96 * 1024 + 512);

  init_kernel<<<1, 64, 0, stream>>>(counts);
  gate_kernel<<<N_TOK / 4, 256, 0, stream>>>(x, gw, gb, counts, tlist, eid, pos, wgt);
  scan_kernel<<<1, 64, 0, stream>>>(counts, offs);
  x2bf_kernel<<<N_TOK * DIM / 1024, 256, 0, stream>>>(x, xb);
  // w1[e][D][H] -> w1t[e][H][D]
  transpose_bf16_kernel<<<dim3(HID / 64, DIM / 64, NE), 256, 0, stream>>>(w1, w1t, DIM, HID);
  // w2[e][H][D] -> w2t[e][D][H]
  transpose_bf16_kernel<<<dim3(DIM / 64, HID / 64, NE), 256, 0, stream>>>(w2, w2t, HID, DIM);
  gemm1_kernel<<<dim3(32, 32, NE), 256, 0, stream>>>(xb, w1t, b1, counts, offs, tlist, hbuf);
  gemm2_kernel<<<dim3(32, 8, NE), 256, 0, stream>>>(hbuf, w2t, b2, counts, offs, ybuf);
  combine_kernel<<<N_TOK, 256, 0, stream>>>(eid, pos, wgt, offs, ybuf, out);
}

// Round 3
// 451.489 us; speedup vs baseline: 2.5551x; 1.8435x over previous
//
#include <hip/hip_runtime.h>
#include <hip/hip_bf16.h>

typedef float f32x4 __attribute__((ext_vector_type(4)));
typedef short s16x8 __attribute__((ext_vector_type(8)));
typedef unsigned short u16;
typedef unsigned short u16x4 __attribute__((ext_vector_type(4)));

#define N_TOK 4096
#define DIM 1024
#define HID 4096
#define NE 8
#define MAXMB 72

__device__ __forceinline__ u16 f2bf(float f) {
  unsigned u = __float_as_uint(f);
  u += 0x7fffu + ((u >> 16) & 1u);   // round-to-nearest-even
  return (u16)(u >> 16);
}

__device__ __forceinline__ void gload16(const u16* g, u16* l) {
  __builtin_amdgcn_global_load_lds(
      (const __attribute__((address_space(1))) unsigned int*)g,
      (__attribute__((address_space(3))) unsigned int*)l, 16, 0, 0);
}

__global__ void init_kernel(int* counts) {
  if (threadIdx.x < NE) counts[threadIdx.x] = 0;
}

__global__ __launch_bounds__(256) void gate_kernel(
    const float* __restrict__ x, const float* __restrict__ gw,
    const float* __restrict__ gb, int* __restrict__ counts,
    int* __restrict__ tlist, int* __restrict__ eid, int* __restrict__ pos,
    float* __restrict__ wgt) {
  int t = blockIdx.x * 4 + (threadIdx.x >> 6);
  int lane = threadIdx.x & 63;
  float acc[NE];
  #pragma unroll
  for (int e = 0; e < NE; ++e) acc[e] = 0.f;
  const float* xr = x + (size_t)t * DIM;
  for (int d = lane; d < DIM; d += 64) {
    float xv = xr[d];
    const float* g = gw + d * NE;
    #pragma unroll
    for (int e = 0; e < NE; ++e) acc[e] += xv * g[e];
  }
  #pragma unroll
  for (int off = 32; off > 0; off >>= 1) {
    #pragma unroll
    for (int e = 0; e < NE; ++e) acc[e] += __shfl_down(acc[e], off);
  }
  if (lane == 0) {
    #pragma unroll
    for (int e = 0; e < NE; ++e) acc[e] += gb[e];
    int i0 = 0; float v0 = acc[0];
    #pragma unroll
    for (int e = 1; e < NE; ++e) if (acc[e] > v0) { v0 = acc[e]; i0 = e; }
    int i1 = -1; float v1 = -1e30f;
    #pragma unroll
    for (int e = 0; e < NE; ++e) if (e != i0 && acc[e] > v1) { v1 = acc[e]; i1 = e; }
    float z = expf(v1 - v0);            // v0 >= v1
    float s0 = 1.f / (1.f + z);
    float s1 = z / (1.f + z);
    int p0 = atomicAdd(&counts[i0], 1);
    tlist[i0 * N_TOK + p0] = t * 2 + 0;
    eid[2 * t] = i0; pos[2 * t] = p0; wgt[2 * t] = s0;
    int p1 = atomicAdd(&counts[i1], 1);
    tlist[i1 * N_TOK + p1] = t * 2 + 1;
    eid[2 * t + 1] = i1; pos[2 * t + 1] = p1; wgt[2 * t + 1] = s1;
  }
}

// Builds dense m-block schedule: experts padded to 128-row slot regions.
__global__ void scan_kernel(const int* __restrict__ counts, int* __restrict__ offs,
                            int* __restrict__ poffs, int* __restrict__ nmb,
                            int* __restrict__ mb2e, int* __restrict__ mb2m0) {
  if (threadIdx.x == 0) {
    int s = 0, p = 0, mb = 0;
    for (int e = 0; e < NE; ++e) {
      offs[e] = s; poffs[e] = p;
      int nb = (counts[e] + 127) >> 7;
      for (int i = 0; i < nb; ++i) { mb2e[mb] = e; mb2m0[mb] = i * 128; ++mb; }
      s += counts[e]; p += nb * 128;
    }
    offs[NE] = s; poffs[NE] = p;
    nmb[0] = mb;
    for (int i = mb; i < MAXMB; ++i) { mb2e[i] = 0; mb2m0[i] = 0; }
  }
}

// x (fp32) -> xb (bf16), elementwise
__global__ __launch_bounds__(256) void x2bf_kernel(const float* __restrict__ x,
                                                   u16* __restrict__ xb) {
  int i = (blockIdx.x * 256 + threadIdx.x) * 4;
  float4 v = *(const float4*)&x[i];
  u16x4 o = {f2bf(v.x), f2bf(v.y), f2bf(v.z), f2bf(v.w)};
  *(u16x4*)&xb[i] = o;
}

// in[e][R][C] fp32 -> out[e][C][R] bf16 (64x64 LDS tile transpose)
__global__ __launch_bounds__(256) void transpose_bf16_kernel(
    const float* __restrict__ in, u16* __restrict__ out, int R, int C) {
  __shared__ u16 tile[64][65];
  int e = blockIdx.z;
  int c0 = blockIdx.x * 64, r0 = blockIdx.y * 64;
  int tid = threadIdx.x;
  int rr = tid >> 4;          // 0..15
  int cc = (tid & 15) * 4;    // 0..60
  const float* src = in + (size_t)e * R * C + (size_t)r0 * C + c0;
  #pragma unroll
  for (int rd = 0; rd < 4; ++rd) {
    int r = rd * 16 + rr;
    float4 v = *(const float4*)&src[(size_t)r * C + cc];
    tile[r][cc + 0] = f2bf(v.x);
    tile[r][cc + 1] = f2bf(v.y);
    tile[r][cc + 2] = f2bf(v.z);
    tile[r][cc + 3] = f2bf(v.w);
  }
  __syncthreads();
  u16* dst = out + (size_t)e * R * C + (size_t)c0 * R + r0;
  #pragma unroll
  for (int rd = 0; rd < 4; ++rd) {
    int oc = rd * 16 + rr;    // output row (= input col)
    u16x4 o;
    o[0] = tile[cc + 0][oc];
    o[1] = tile[cc + 1][oc];
    o[2] = tile[cc + 2][oc];
    o[3] = tile[cc + 3][oc];
    *(u16x4*)&dst[(size_t)oc * R + cc] = o;
  }
}

// GEMM1: h[pslot, H] = relu(x[token, D] * w1t[e]^T + b1[e]) -> bf16
__global__ __launch_bounds__(256) void gemm1_kernel(
    const u16* __restrict__ xb, const u16* __restrict__ w1t,
    const float* __restrict__ b1, const int* __restrict__ counts,
    const int* __restrict__ poffs, const int* __restrict__ nmb,
    const int* __restrict__ mb2e, const int* __restrict__ mb2m0,
    const int* __restrict__ tlist, u16* __restrict__ hbuf) {
  int mb = blockIdx.x;
  if (mb >= nmb[0]) return;
  int e = mb2e[mb];
  int m0 = mb2m0[mb];
  int ne = counts[e];
  int n0 = blockIdx.y * 128;
  int tid = threadIdx.x;

  __shared__ u16 Als[128 * 32];
  __shared__ u16 Bls[128 * 32];

  int sr = tid >> 2;          // 0..63 : row within 64-row half
  int sc = (tid & 3) * 8;     // k element offset for 16B chunk
  const u16* aAdr[2];
  const u16* bAdr[2];
  u16* aLds[2];
  u16* bLds[2];
  #pragma unroll
  for (int r = 0; r < 2; ++r) {
    int tr = m0 + r * 64 + sr;
    int idx = tr < ne ? tr : ne - 1;
    int token = tlist[e * N_TOK + idx] >> 1;
    aAdr[r] = xb + (size_t)token * DIM + sc;
    int nr = n0 + r * 64 + sr;
    bAdr[r] = w1t + ((size_t)e * HID + nr) * DIM + sc;
    aLds[r] = &Als[r * 2048 + tid * 8];
    bLds[r] = &Bls[r * 2048 + tid * 8];
  }

  int lane = tid & 63;
  int wv = tid >> 6;
  int wr = (wv >> 1) * 64, wc = (wv & 1) * 64;
  int fr = lane & 15, fq = lane >> 4;

  f32x4 acc[4][4];
  #pragma unroll
  for (int m = 0; m < 4; ++m)
    #pragma unroll
    for (int n = 0; n < 4; ++n) { f32x4 z = {0.f, 0.f, 0.f, 0.f}; acc[m][n] = z; }

  for (int k0 = 0; k0 < DIM; k0 += 32) {
    __syncthreads();
    gload16(aAdr[0] + k0, aLds[0]);
    gload16(aAdr[1] + k0, aLds[1]);
    gload16(bAdr[0] + k0, bLds[0]);
    gload16(bAdr[1] + k0, bLds[1]);
    __syncthreads();
    s16x8 af[4], bfr[4];
    #pragma unroll
    for (int m = 0; m < 4; ++m)
      af[m] = *(const s16x8*)&Als[(wr + m * 16 + fr) * 32 + fq * 8];
    #pragma unroll
    for (int n = 0; n < 4; ++n)
      bfr[n] = *(const s16x8*)&Bls[(wc + n * 16 + fr) * 32 + fq * 8];
    #pragma unroll
    for (int m = 0; m < 4; ++m)
      #pragma unroll
      for (int n = 0; n < 4; ++n)
        acc[m][n] = __builtin_amdgcn_mfma_f32_16x16x32_bf16(af[m], bfr[n], acc[m][n], 0, 0, 0);
  }

  int pbase = poffs[e] + m0;
  float bias[4];
  #pragma unroll
  for (int n = 0; n < 4; ++n) bias[n] = b1[e * HID + n0 + wc + n * 16 + fr];
  #pragma unroll
  for (int m = 0; m < 4; ++m) {
    #pragma unroll
    for (int j = 0; j < 4; ++j) {
      int row = wr + m * 16 + fq * 4 + j;
      if (m0 + row < ne) {
        u16* hr = hbuf + (size_t)(pbase + row) * HID + n0;
        #pragma unroll
        for (int n = 0; n < 4; ++n) {
          int col = wc + n * 16 + fr;
          float v = acc[m][n][j] + bias[n];
          hr[col] = f2bf(fmaxf(v, 0.f));
        }
      }
    }
  }
}

// GEMM2: y[pslot, D] = h[pslot, H] * w2t[e]^T + b2[e] -> fp32
__global__ __launch_bounds__(256) void gemm2_kernel(
    const u16* __restrict__ hbuf, const u16* __restrict__ w2t,
    const float* __restrict__ b2, const int* __restrict__ counts,
    const int* __restrict__ poffs, const int* __restrict__ nmb,
    const int* __restrict__ mb2e, const int* __restrict__ mb2m0,
    float* __restrict__ ybuf) {
  int mb = blockIdx.x;
  if (mb >= nmb[0]) return;
  int e = mb2e[mb];
  int m0 = mb2m0[mb];
  int ne = counts[e];
  int n0 = blockIdx.y * 128;
  int tid = threadIdx.x;
  int pbase = poffs[e] + m0;

  __shared__ u16 Als[128 * 32];
  __shared__ u16 Bls[128 * 32];

  int sr = tid >> 2;
  int sc = (tid & 3) * 8;
  const u16* aAdr[2];
  const u16* bAdr[2];
  u16* aLds[2];
  u16* bLds[2];
  #pragma unroll
  for (int r = 0; r < 2; ++r) {
    int ar = m0 + r * 64 + sr;
    int idx = ar < ne ? ar : ne - 1;
    aAdr[r] = hbuf + (size_t)(poffs[e] + idx) * HID + sc;
    int nr = n0 + r * 64 + sr;
    bAdr[r] = w2t + ((size_t)e * DIM + nr) * HID + sc;
    aLds[r] = &Als[r * 2048 + tid * 8];
    bLds[r] = &Bls[r * 2048 + tid * 8];
  }

  int lane = tid & 63;
  int wv = tid >> 6;
  int wr = (wv >> 1) * 64, wc = (wv & 1) * 64;
  int fr = lane & 15, fq = lane >> 4;

  f32x4 acc[4][4];
  #pragma unroll
  for (int m = 0; m < 4; ++m)
    #pragma unroll
    for (int n = 0; n < 4; ++n) { f32x4 z = {0.f, 0.f, 0.f, 0.f}; acc[m][n] = z; }

  for (int k0 = 0; k0 < HID; k0 += 32) {
    __syncthreads();
    gload16(aAdr[0] + k0, aLds[0]);
    gload16(aAdr[1] + k0, aLds[1]);
    gload16(bAdr[0] + k0, bLds[0]);
    gload16(bAdr[1] + k0, bLds[1]);
    __syncthreads();
    s16x8 af[4], bfr[4];
    #pragma unroll
    for (int m = 0; m < 4; ++m)
      af[m] = *(const s16x8*)&Als[(wr + m * 16 + fr) * 32 + fq * 8];
    #pragma unroll
    for (int n = 0; n < 4; ++n)
      bfr[n] = *(const s16x8*)&Bls[(wc + n * 16 + fr) * 32 + fq * 8];
    #pragma unroll
    for (int m = 0; m < 4; ++m)
      #pragma unroll
      for (int n = 0; n < 4; ++n)
        acc[m][n] = __builtin_amdgcn_mfma_f32_16x16x32_bf16(af[m], bfr[n], acc[m][n], 0, 0, 0);
  }

  float bias[4];
  #pragma unroll
  for (int n = 0; n < 4; ++n) bias[n] = b2[e * DIM + n0 + wc + n * 16 + fr];
  #pragma unroll
  for (int m = 0; m < 4; ++m) {
    #pragma unroll
    for (int j = 0; j < 4; ++j) {
      int row = wr + m * 16 + fq * 4 + j;
      if (m0 + row < ne) {
        float* yr = ybuf + (size_t)(pbase + row) * DIM + n0;
        #pragma unroll
        for (int n = 0; n < 4; ++n) {
          int col = wc + n * 16 + fr;
          yr[col] = acc[m][n][j] + bias[n];
        }
      }
    }
  }
}

__global__ __launch_bounds__(256) void combine_kernel(
    const int* __restrict__ eid, const int* __restrict__ pos,
    const float* __restrict__ wgt, const int* __restrict__ poffs,
    const float* __restrict__ ybuf, float* __restrict__ out) {
  int t = blockIdx.x;
  int e0 = eid[2 * t], e1 = eid[2 * t + 1];
  float w0 = wgt[2 * t], w1v = wgt[2 * t + 1];
  size_t g0 = (size_t)(poffs[e0] + pos[2 * t]) * DIM;
  size_t g1 = (size_t)(poffs[e1] + pos[2 * t + 1]) * DIM;
  int d = threadIdx.x * 4;
  float4 y0 = *(const float4*)&ybuf[g0 + d];
  float4 y1 = *(const float4*)&ybuf[g1 + d];
  float4 o;
  o.x = w0 * y0.x + w1v * y1.x;
  o.y = w0 * y0.y + w1v * y1.y;
  o.z = w0 * y0.z + w1v * y1.z;
  o.w = w0 * y0.w + w1v * y1.w;
  *(float4*)&out[(size_t)t * DIM + d] = o;
}

extern "C" void kernel_launch(void* const* d_in, const int* in_sizes, int n_in,
                              void* d_out, int out_size, void* d_ws, size_t ws_size,
                              hipStream_t stream) {
  const float* x  = (const float*)d_in[0];
  const float* gw = (const float*)d_in[1];
  const float* gb = (const float*)d_in[2];
  const float* w1 = (const float*)d_in[3];
  const float* b1 = (const float*)d_in[4];
  const float* w2 = (const float*)d_in[5];
  const float* b2 = (const float*)d_in[6];
  float* out = (float*)d_out;

  char* ws = (char*)d_ws;
  const size_t MB = 1ull << 20;
  // layout: w1t 64MB (ybuf aliases here after gemm1) | w2t 64MB | xb 8MB | hbuf 72MB | meta
  u16*   w1t    = (u16*)(ws);
  float* ybuf   = (float*)(ws);              // alias: w1t dead before gemm2 writes ybuf
  u16*   w2t    = (u16*)(ws + 64 * MB);
  u16*   xb     = (u16*)(ws + 128 * MB);
  u16*   hbuf   = (u16*)(ws + 136 * MB);
  char*  meta   = ws + 208 * MB;
  int*   eid    = (int*)(meta);
  int*   pos    = (int*)(meta + 32 * 1024);
  float* wgt    = (float*)(meta + 64 * 1024);
  int*   counts = (int*)(meta + 96 * 1024);
  int*   offs   = (int*)(meta + 96 * 1024 + 256);
  int*   poffs  = (int*)(meta + 96 * 1024 + 512);
  int*   nmb    = (int*)(meta + 96 * 1024 + 768);
  int*   mb2e   = (int*)(meta + 96 * 1024 + 1024);
  int*   mb2m0  = (int*)(meta + 96 * 1024 + 2048);
  int*   tlist  = (int*)(meta + 128 * 1024);

  init_kernel<<<1, 64, 0, stream>>>(counts);
  gate_kernel<<<N_TOK / 4, 256, 0, stream>>>(x, gw, gb, counts, tlist, eid, pos, wgt);
  scan_kernel<<<1, 64, 0, stream>>>(counts, offs, poffs, nmb, mb2e, mb2m0);
  x2bf_kernel<<<N_TOK * DIM / 1024, 256, 0, stream>>>(x, xb);
  // w1[e][D][H] -> w1t[e][H][D]
  transpose_bf16_kernel<<<dim3(HID / 64, DIM / 64, NE), 256, 0, stream>>>(w1, w1t, DIM, HID);
  // w2[e][H][D] -> w2t[e][D][H]
  transpose_bf16_kernel<<<dim3(DIM / 64, HID / 64, NE), 256, 0, stream>>>(w2, w2t, HID, DIM);
  gemm1_kernel<<<dim3(MAXMB, 32), 256, 0, stream>>>(xb, w1t, b1, counts, poffs, nmb, mb2e, mb2m0, tlist, hbuf);
  gemm2_kernel<<<dim3(MAXMB, 8), 256, 0, stream>>>(hbuf, w2t, b2, counts, poffs, nmb, mb2e, mb2m0, ybuf);
  combine_kernel<<<N_TOK, 256, 0, stream>>>(eid, pos, wgt, poffs, ybuf, out);
}